// Round 1
// baseline (580.912 us; speedup 1.0000x reference)
//
#include <hip/hip_runtime.h>
#include <hip/hip_bf16.h>

// Problem constants (from reference)
#define L_DIM 16384
#define H_DIM 512
#define P_DIM 512
#define T_CH  64          // chunk length for the scan
#define NC    (L_DIM / T_CH)   // 256 chunks
#define LP    ((size_t)L_DIM * P_DIM)
#define NCP   ((size_t)NC * P_DIM)

// ---------------------------------------------------------------------------
// prep: ZOH discretization + gamma + lambda-power table (tiny, 1 block)
// ---------------------------------------------------------------------------
__global__ __launch_bounds__(P_DIM) void prep_kernel(
    const float* __restrict__ Lre, const float* __restrict__ Lim,
    const float* __restrict__ log_step,
    float* __restrict__ lbr, float* __restrict__ lbi,
    float* __restrict__ gre, float* __restrict__ gim,
    float* __restrict__ powr, float* __restrict__ powi)
{
    int p = threadIdx.x;
    float st = expf(log_step[p]);
    float ar = Lre[p] * st, ai = Lim[p] * st;
    float er = expf(ar);
    float lr = er * cosf(ai);
    float li = er * sinf(ai);
    lbr[p] = lr; lbi[p] = li;
    // gamma = (lambda_bar - 1) / Lambda   (complex divide)
    float den = Lre[p] * Lre[p] + Lim[p] * Lim[p];
    float x = lr - 1.0f, y = li;
    gre[p] = (x * Lre[p] + y * Lim[p]) / den;
    gim[p] = (y * Lre[p] - x * Lim[p]) / den;
    // powers lambda_bar^k, k = 0..T_CH
    float pr = 1.0f, pi = 0.0f;
    powr[p] = pr; powi[p] = pi;
    for (int k = 1; k <= T_CH; ++k) {
        float nr = pr * lr - pi * li;
        float ni = pr * li + pi * lr;
        pr = nr; pi = ni;
        powr[(size_t)k * P_DIM + p] = pr;
        powi[(size_t)k * P_DIM + p] = pi;
    }
}

// ---------------------------------------------------------------------------
// gemm_bu: S_re = u @ B_re^T, S_im = u @ B_im^T in one pass (shared A tile),
// epilogue applies complex gamma per column:
//   Bu_re = g_r*S_re - g_i*S_im ; Bu_im = g_r*S_im + g_i*S_re
// A = u (L,H) row-major; B = (P,H) row-major (NT GEMM). Tile 64x64x16.
// ---------------------------------------------------------------------------
#define BM 64
#define BN 64
#define BK 16
#define PAD 4

__global__ __launch_bounds__(256) void gemm_bu(
    const float* __restrict__ u,
    const float* __restrict__ Bre, const float* __restrict__ Bim,
    const float* __restrict__ gre, const float* __restrict__ gim,
    float* __restrict__ bur, float* __restrict__ bui)
{
    __shared__ float As [BK][BM + PAD];
    __shared__ float Bs1[BK][BN + PAD];
    __shared__ float Bs2[BK][BN + PAD];

    int tid = threadIdx.x;
    int tx = tid & 15, ty = tid >> 4;
    int m0 = blockIdx.x * BM;   // along L
    int n0 = blockIdx.y * BN;   // along P

    float acc1[4][4] = {{0.f}};
    float acc2[4][4] = {{0.f}};

    int lrow = tid >> 2;        // 0..63
    int lk   = (tid & 3) * 4;   // 0,4,8,12

    for (int k0 = 0; k0 < H_DIM; k0 += BK) {
        float4 av = *(const float4*)&u  [(size_t)(m0 + lrow) * H_DIM + k0 + lk];
        float4 b1 = *(const float4*)&Bre[(size_t)(n0 + lrow) * H_DIM + k0 + lk];
        float4 b2 = *(const float4*)&Bim[(size_t)(n0 + lrow) * H_DIM + k0 + lk];
        __syncthreads();
        As [lk+0][lrow] = av.x; As [lk+1][lrow] = av.y; As [lk+2][lrow] = av.z; As [lk+3][lrow] = av.w;
        Bs1[lk+0][lrow] = b1.x; Bs1[lk+1][lrow] = b1.y; Bs1[lk+2][lrow] = b1.z; Bs1[lk+3][lrow] = b1.w;
        Bs2[lk+0][lrow] = b2.x; Bs2[lk+1][lrow] = b2.y; Bs2[lk+2][lrow] = b2.z; Bs2[lk+3][lrow] = b2.w;
        __syncthreads();
        #pragma unroll
        for (int k = 0; k < BK; ++k) {
            float4 a  = *(const float4*)&As [k][ty * 4];
            float4 p1 = *(const float4*)&Bs1[k][tx * 4];
            float4 p2 = *(const float4*)&Bs2[k][tx * 4];
            float avv[4] = {a.x, a.y, a.z, a.w};
            float bv1[4] = {p1.x, p1.y, p1.z, p1.w};
            float bv2[4] = {p2.x, p2.y, p2.z, p2.w};
            #pragma unroll
            for (int i = 0; i < 4; ++i)
                #pragma unroll
                for (int j = 0; j < 4; ++j) {
                    acc1[i][j] = fmaf(avv[i], bv1[j], acc1[i][j]);
                    acc2[i][j] = fmaf(avv[i], bv2[j], acc2[i][j]);
                }
        }
    }

    #pragma unroll
    for (int j = 0; j < 4; ++j) {
        int pc = n0 + tx * 4 + j;
        float g_r = gre[pc], g_i = gim[pc];
        #pragma unroll
        for (int i = 0; i < 4; ++i) {
            size_t row = (size_t)(m0 + ty * 4 + i);
            size_t idx = row * P_DIM + pc;
            bur[idx] = g_r * acc1[i][j] - g_i * acc2[i][j];
            bui[idx] = g_r * acc2[i][j] + g_i * acc1[i][j];
        }
    }
}

// ---------------------------------------------------------------------------
// scan phase A: chunk-local inclusive scan, in place over Bu. One block per
// chunk, one thread per channel. Writes chunk-final state to bc.
// ---------------------------------------------------------------------------
__global__ __launch_bounds__(P_DIM) void scan_local(
    float* __restrict__ bur, float* __restrict__ bui,
    const float* __restrict__ lbr, const float* __restrict__ lbi,
    float* __restrict__ bcr, float* __restrict__ bci)
{
    int p = threadIdx.x;
    int c = blockIdx.x;
    float lr = lbr[p], li = lbi[p];
    float xr = 0.f, xi = 0.f;
    size_t base = (size_t)c * T_CH * P_DIM + p;
    for (int k = 0; k < T_CH; ++k) {
        size_t idx = base + (size_t)k * P_DIM;
        float br = bur[idx];
        float bi = bui[idx];
        float nr = fmaf(lr, xr, fmaf(-li, xi, br));
        float ni = fmaf(lr, xi, fmaf( li, xr, bi));
        xr = nr; xi = ni;
        bur[idx] = xr;
        bui[idx] = xi;
    }
    bcr[(size_t)c * P_DIM + p] = xr;
    bci[(size_t)c * P_DIM + p] = xi;
}

// ---------------------------------------------------------------------------
// scan phase B: exclusive scan across chunk aggregates (1 block, serial NC).
// carry[c] = state at end of chunk c-1 (carry[0] = 0).
// ---------------------------------------------------------------------------
__global__ __launch_bounds__(P_DIM) void scan_chunks(
    const float* __restrict__ bcr, const float* __restrict__ bci,
    const float* __restrict__ powr, const float* __restrict__ powi,
    float* __restrict__ carr, float* __restrict__ cari)
{
    int p = threadIdx.x;
    float lr = powr[(size_t)T_CH * P_DIM + p];   // lambda_bar^T
    float li = powi[(size_t)T_CH * P_DIM + p];
    float sr = 0.f, si = 0.f;
    for (int c = 0; c < NC; ++c) {
        size_t idx = (size_t)c * P_DIM + p;
        carr[idx] = sr; cari[idx] = si;
        float br = bcr[idx], bi = bci[idx];
        float nr = fmaf(lr, sr, fmaf(-li, si, br));
        float ni = fmaf(lr, si, fmaf( li, sr, bi));
        sr = nr; si = ni;
    }
}

// ---------------------------------------------------------------------------
// scan phase C: fixup x_t += lambda^{k+1} * carry_in[chunk]  (in place)
// ---------------------------------------------------------------------------
__global__ __launch_bounds__(256) void scan_fixup(
    float* __restrict__ xr, float* __restrict__ xi,
    const float* __restrict__ carr, const float* __restrict__ cari,
    const float* __restrict__ powr, const float* __restrict__ powi)
{
    size_t i = (size_t)blockIdx.x * 256 + threadIdx.x;
    int p = (int)(i & (P_DIM - 1));
    int l = (int)(i >> 9);            // P_DIM = 512 = 2^9
    int c = l >> 6;                   // T_CH = 64
    int k = l & (T_CH - 1);
    float pr = powr[(size_t)(k + 1) * P_DIM + p];
    float pi = powi[(size_t)(k + 1) * P_DIM + p];
    float cr = carr[(size_t)c * P_DIM + p];
    float ci = cari[(size_t)c * P_DIM + p];
    float ar = xr[i], ai = xi[i];
    xr[i] = fmaf(pr, cr, fmaf(-pi, ci, ar));
    xi[i] = fmaf(pr, ci, fmaf( pi, cr, ai));
}

// ---------------------------------------------------------------------------
// gemm_y: out = xs_re @ Cre^T - xs_im @ Cim^T + D*u   (NT GEMM, K = P)
// ---------------------------------------------------------------------------
__global__ __launch_bounds__(256) void gemm_y(
    const float* __restrict__ xr, const float* __restrict__ xi,
    const float* __restrict__ Cre, const float* __restrict__ Cim,
    const float* __restrict__ D, const float* __restrict__ u,
    float* __restrict__ out)
{
    __shared__ float As1[BK][BM + PAD];
    __shared__ float As2[BK][BM + PAD];
    __shared__ float Bs1[BK][BN + PAD];
    __shared__ float Bs2[BK][BN + PAD];

    int tid = threadIdx.x;
    int tx = tid & 15, ty = tid >> 4;
    int m0 = blockIdx.x * BM;   // along L
    int n0 = blockIdx.y * BN;   // along H

    float acc[4][4] = {{0.f}};

    int lrow = tid >> 2;
    int lk   = (tid & 3) * 4;

    for (int k0 = 0; k0 < P_DIM; k0 += BK) {
        float4 a1 = *(const float4*)&xr [(size_t)(m0 + lrow) * P_DIM + k0 + lk];
        float4 a2 = *(const float4*)&xi [(size_t)(m0 + lrow) * P_DIM + k0 + lk];
        float4 b1 = *(const float4*)&Cre[(size_t)(n0 + lrow) * P_DIM + k0 + lk];
        float4 b2 = *(const float4*)&Cim[(size_t)(n0 + lrow) * P_DIM + k0 + lk];
        __syncthreads();
        As1[lk+0][lrow] = a1.x; As1[lk+1][lrow] = a1.y; As1[lk+2][lrow] = a1.z; As1[lk+3][lrow] = a1.w;
        As2[lk+0][lrow] = a2.x; As2[lk+1][lrow] = a2.y; As2[lk+2][lrow] = a2.z; As2[lk+3][lrow] = a2.w;
        Bs1[lk+0][lrow] = b1.x; Bs1[lk+1][lrow] = b1.y; Bs1[lk+2][lrow] = b1.z; Bs1[lk+3][lrow] = b1.w;
        Bs2[lk+0][lrow] = b2.x; Bs2[lk+1][lrow] = b2.y; Bs2[lk+2][lrow] = b2.z; Bs2[lk+3][lrow] = b2.w;
        __syncthreads();
        #pragma unroll
        for (int k = 0; k < BK; ++k) {
            float4 va1 = *(const float4*)&As1[k][ty * 4];
            float4 va2 = *(const float4*)&As2[k][ty * 4];
            float4 vb1 = *(const float4*)&Bs1[k][tx * 4];
            float4 vb2 = *(const float4*)&Bs2[k][tx * 4];
            float a1v[4] = {va1.x, va1.y, va1.z, va1.w};
            float a2v[4] = {va2.x, va2.y, va2.z, va2.w};
            float b1v[4] = {vb1.x, vb1.y, vb1.z, vb1.w};
            float b2v[4] = {vb2.x, vb2.y, vb2.z, vb2.w};
            #pragma unroll
            for (int i = 0; i < 4; ++i)
                #pragma unroll
                for (int j = 0; j < 4; ++j) {
                    acc[i][j] = fmaf(a1v[i],  b1v[j], acc[i][j]);
                    acc[i][j] = fmaf(-a2v[i], b2v[j], acc[i][j]);
                }
        }
    }

    #pragma unroll
    for (int j = 0; j < 4; ++j) {
        int h = n0 + tx * 4 + j;
        float dv = D[h];
        #pragma unroll
        for (int i = 0; i < 4; ++i) {
            size_t row = (size_t)(m0 + ty * 4 + i);
            size_t idx = row * H_DIM + h;
            out[idx] = acc[i][j] + dv * u[idx];
        }
    }
}

// ---------------------------------------------------------------------------
extern "C" void kernel_launch(void* const* d_in, const int* in_sizes, int n_in,
                              void* d_out, int out_size, void* d_ws, size_t ws_size,
                              hipStream_t stream)
{
    const float* u        = (const float*)d_in[0];
    const float* Lre      = (const float*)d_in[1];
    const float* Lim      = (const float*)d_in[2];
    const float* Bre      = (const float*)d_in[3];
    const float* Bim      = (const float*)d_in[4];
    const float* Cre      = (const float*)d_in[5];
    const float* Cim      = (const float*)d_in[6];
    const float* D        = (const float*)d_in[7];
    const float* log_step = (const float*)d_in[8];
    float* out = (float*)d_out;

    // workspace layout (floats)
    float* ws   = (float*)d_ws;
    float* bur  = ws;                 // L*P
    float* bui  = bur + LP;           // L*P
    float* bcr  = bui + LP;           // NC*P
    float* bci  = bcr + NCP;
    float* carr = bci + NCP;
    float* cari = carr + NCP;
    float* lbr  = cari + NCP;         // P
    float* lbi  = lbr + P_DIM;
    float* gre  = lbi + P_DIM;
    float* gim  = gre + P_DIM;
    float* powr = gim + P_DIM;        // (T+1)*P
    float* powi = powr + (size_t)(T_CH + 1) * P_DIM;

    prep_kernel<<<1, P_DIM, 0, stream>>>(Lre, Lim, log_step, lbr, lbi, gre, gim, powr, powi);

    dim3 gbu(L_DIM / BM, P_DIM / BN);
    gemm_bu<<<gbu, 256, 0, stream>>>(u, Bre, Bim, gre, gim, bur, bui);

    scan_local<<<NC, P_DIM, 0, stream>>>(bur, bui, lbr, lbi, bcr, bci);
    scan_chunks<<<1, P_DIM, 0, stream>>>(bcr, bci, powr, powi, carr, cari);
    scan_fixup<<<(int)(LP / 256), 256, 0, stream>>>(bur, bui, carr, cari, powr, powi);

    dim3 gy(L_DIM / BM, H_DIM / BN);
    gemm_y<<<gy, 256, 0, stream>>>(bur, bui, Cre, Cim, D, u, out);
}

// Round 2
// 214.666 us; speedup vs baseline: 2.7061x; 2.7061x over previous
//
#include <hip/hip_runtime.h>
#include <stdint.h>

#define L_DIM 16384
#define H_DIM 512
#define P_DIM 512
#define T_CH  64
#define NC    (L_DIM / T_CH)      // 256 chunks
#define LP    ((size_t)L_DIM * P_DIM)
#define LH    ((size_t)L_DIM * H_DIM)
#define NCP   ((size_t)NC * P_DIM)

typedef unsigned short u16;
typedef __attribute__((ext_vector_type(8))) short short8v;   // 8 bf16 = 4 VGPRs
typedef __attribute__((ext_vector_type(4))) float f32x4;

// ---- bf16 helpers (round-to-nearest-even-ish split) ------------------------
__device__ __forceinline__ u16 f2bf(float x) {
    union { float f; uint32_t u; } c; c.f = x;
    uint32_t r = (c.u + 0x7fffu + ((c.u >> 16) & 1u)) >> 16;
    return (u16)r;
}
__device__ __forceinline__ float bf2f(u16 h) {
    union { uint32_t u; float f; } c; c.u = ((uint32_t)h) << 16;
    return c.f;
}

// ---- async global->LDS, 16B per lane, wave-uniform LDS base ----------------
__device__ __forceinline__ void gload16(const void* g, void* lds) {
    __builtin_amdgcn_global_load_lds(
        (const __attribute__((address_space(1))) void*)g,
        (__attribute__((address_space(3))) void*)(uintptr_t)lds,
        16, 0, 0);
}

__device__ __forceinline__ f32x4 mfma_bf16(short8v a, short8v b, f32x4 c) {
    return __builtin_amdgcn_mfma_f32_16x16x32_bf16(a, b, c, 0, 0, 0);
}

// ---------------------------------------------------------------------------
// prep: ZOH discretization. lambda_bar, lambda_bar^64, gamma=(lb-1)/Lambda
// ---------------------------------------------------------------------------
__global__ __launch_bounds__(P_DIM) void prep_kernel(
    const float* __restrict__ Lre, const float* __restrict__ Lim,
    const float* __restrict__ log_step,
    float* __restrict__ lbr, float* __restrict__ lbi,
    float* __restrict__ l64r, float* __restrict__ l64i,
    float* __restrict__ gre, float* __restrict__ gim)
{
    int p = threadIdx.x;
    float st = expf(log_step[p]);
    float ar = Lre[p] * st, ai = Lim[p] * st;
    float er = expf(ar);
    float lr = er * cosf(ai), li = er * sinf(ai);
    lbr[p] = lr; lbi[p] = li;
    float den = Lre[p] * Lre[p] + Lim[p] * Lim[p];
    float x = lr - 1.0f, y = li;
    gre[p] = (x * Lre[p] + y * Lim[p]) / den;
    gim[p] = (y * Lre[p] - x * Lim[p]) / den;
    float pr = 1.f, pi2 = 0.f;
    for (int k = 0; k < T_CH; ++k) {
        float nr = pr * lr - pi2 * li;
        float ni = pr * li + pi2 * lr;
        pr = nr; pi2 = ni;
    }
    l64r[p] = pr; l64i[p] = pi2;
}

// ---------------------------------------------------------------------------
// convert u (L,H) fp32 -> hi/lo bf16
// ---------------------------------------------------------------------------
__global__ __launch_bounds__(256) void convert_u(
    const float* __restrict__ u, u16* __restrict__ uh, u16* __restrict__ ul)
{
    size_t i = ((size_t)blockIdx.x * 256 + threadIdx.x) * 4;
    float4 v = *(const float4*)(u + i);
    ushort4 h, l;
    h.x = f2bf(v.x); l.x = f2bf(v.x - bf2f(h.x));
    h.y = f2bf(v.y); l.y = f2bf(v.y - bf2f(h.y));
    h.z = f2bf(v.z); l.z = f2bf(v.z - bf2f(h.z));
    h.w = f2bf(v.w); l.w = f2bf(v.w - bf2f(h.w));
    *(ushort4*)(uh + i) = h;
    *(ushort4*)(ul + i) = l;
}

// ---------------------------------------------------------------------------
// Bcat (1024 x 1536): rows 0..511 = Bbar_re, 512..1023 = Bbar_im, where
// Bbar = gamma * (Bre + i Bim). K-segments: [hi | hi | lo] to pair with
// A-segments [u_hi | u_lo | u_hi].
// ---------------------------------------------------------------------------
__global__ __launch_bounds__(256) void build_bcat(
    const float* __restrict__ Bre, const float* __restrict__ Bim,
    const float* __restrict__ gre, const float* __restrict__ gim,
    u16* __restrict__ Bcat)
{
    int idx = blockIdx.x * 256 + threadIdx.x;   // p*H + h
    int p = idx >> 9, h = idx & 511;
    float br = Bre[idx], bi = Bim[idx];
    float gr = gre[p], gi = gim[p];
    float vr = gr * br - gi * bi;
    float vi = gr * bi + gi * br;
    u16 rh = f2bf(vr); u16 rl = f2bf(vr - bf2f(rh));
    u16 ih = f2bf(vi); u16 il = f2bf(vi - bf2f(ih));
    size_t rowr = (size_t)p * 1536;
    size_t rowi = (size_t)(512 + p) * 1536;
    Bcat[rowr + h] = rh; Bcat[rowr + 512 + h] = rh; Bcat[rowr + 1024 + h] = rl;
    Bcat[rowi + h] = ih; Bcat[rowi + 512 + h] = ih; Bcat[rowi + 1024 + h] = il;
}

// ---------------------------------------------------------------------------
// Ccat (512 x 3072): per row h: [Cre_hi | Cre_hi | Cre_lo | -Cim_hi | -Cim_hi | -Cim_lo]
// pairs with A-segments [xr_hi | xr_lo | xr_hi | xi_hi | xi_lo | xi_hi].
// ---------------------------------------------------------------------------
__global__ __launch_bounds__(256) void build_ccat(
    const float* __restrict__ Cre, const float* __restrict__ Cim,
    u16* __restrict__ Ccat)
{
    int idx = blockIdx.x * 256 + threadIdx.x;   // h*P + p
    int h = idx >> 9, p = idx & 511;
    float cr = Cre[idx], ci = -Cim[idx];
    u16 crh = f2bf(cr); u16 crl = f2bf(cr - bf2f(crh));
    u16 cih = f2bf(ci); u16 cil = f2bf(ci - bf2f(cih));
    size_t row = (size_t)h * 3072;
    Ccat[row + p]        = crh; Ccat[row + 512 + p]  = crh; Ccat[row + 1024 + p] = crl;
    Ccat[row + 1536 + p] = cih; Ccat[row + 2048 + p] = cih; Ccat[row + 2560 + p] = cil;
}

// ---------------------------------------------------------------------------
// MFMA GEMM, 128x128 tile, BK=64, 4 waves (each 64x64), global_load_lds
// staging with XOR-swizzled source so swizzled ds_read_b128 is conflict-free.
// A is segmented along K in 512-element segments with per-segment base ptrs.
// MODE 0: C (L,1024) -> split into two fp32 arrays (re | im), no epilogue.
// MODE 1: C (L,512)  -> out = acc + D[col]*u[row,col].
// ---------------------------------------------------------------------------
template<int KTOT, int NBN, int MODE>
__global__ __launch_bounds__(256, 2) void gemm_mfma(
    const u16* __restrict__ A0, const u16* __restrict__ A1, const u16* __restrict__ A2,
    const u16* __restrict__ A3, const u16* __restrict__ A4, const u16* __restrict__ A5,
    const u16* __restrict__ Bmat,
    float* __restrict__ O0, float* __restrict__ O1,
    const float* __restrict__ Dvec, const float* __restrict__ uIn)
{
    __shared__ u16 Als[128 * 64];
    __shared__ u16 Bls[128 * 64];

    const u16* Aseg[6] = {A0, A1, A2, A3, A4, A5};

    // XCD-chunked block mapping: same-M blocks land on the same XCD (b%8).
    int b = blockIdx.x;
    int m = (b & 7) * 16 + b / (8 * NBN);
    int n = (b >> 3) & (NBN - 1);
    int m0 = m * 128, n0 = n * 128;

    int tid = threadIdx.x;
    int w = tid >> 6, lane = tid & 63;
    int wm = w >> 1, wn = w & 1;

    f32x4 acc[4][4];
    #pragma unroll
    for (int i = 0; i < 4; ++i)
        #pragma unroll
        for (int j = 0; j < 4; ++j) acc[i][j] = (f32x4)0.f;

    int lr8  = lane >> 3;   // 0..7
    int slin = lane & 7;    // linear 16B slot this lane writes

    char* AlsB = (char*)&Als[0];
    char* BlsB = (char*)&Bls[0];

    const int NSEG = KTOT / 512;
    #pragma unroll
    for (int seg = 0; seg < NSEG; ++seg) {
        const u16* Ap = Aseg[seg];
        for (int k8 = 0; k8 < 8; ++k8) {
            int ko = k8 * 64;           // K offset within segment (elements)
            int kB = seg * 512 + ko;    // K offset within full KTOT (for B)

            __syncthreads();            // previous tile fully consumed
            #pragma unroll
            for (int c = 0; c < 4; ++c) {
                int sidx = w * 4 + c;           // 16 wave-issues cover 16KB
                int r = sidx * 8 + lr8;         // tile row this lane feeds
                int g = slin ^ (r & 7);         // pre-swizzled source slot
                const u16* ga = Ap + (size_t)(m0 + r) * 512 + ko + g * 8;
                gload16(ga, AlsB + sidx * 1024);
                const u16* gb = Bmat + (size_t)(n0 + r) * KTOT + kB + g * 8;
                gload16(gb, BlsB + sidx * 1024);
            }
            asm volatile("s_waitcnt vmcnt(0)" ::: "memory");
            __syncthreads();            // staged tile visible

            short8v a[4][2], bf[4][2];
            #pragma unroll
            for (int mm = 0; mm < 4; ++mm)
                #pragma unroll
                for (int kk = 0; kk < 2; ++kk) {
                    int row = wm * 64 + mm * 16 + (lane & 15);
                    int sl  = kk * 4 + (lane >> 4);
                    int off = row * 128 + ((sl ^ (lane & 7)) << 4);
                    a[mm][kk] = *(const short8v*)(AlsB + off);
                }
            #pragma unroll
            for (int nn = 0; nn < 4; ++nn)
                #pragma unroll
                for (int kk = 0; kk < 2; ++kk) {
                    int row = wn * 64 + nn * 16 + (lane & 15);
                    int sl  = kk * 4 + (lane >> 4);
                    int off = row * 128 + ((sl ^ (lane & 7)) << 4);
                    bf[nn][kk] = *(const short8v*)(BlsB + off);
                }
            #pragma unroll
            for (int mm = 0; mm < 4; ++mm)
                #pragma unroll
                for (int nn = 0; nn < 4; ++nn) {
                    acc[mm][nn] = mfma_bf16(a[mm][0], bf[nn][0], acc[mm][nn]);
                    acc[mm][nn] = mfma_bf16(a[mm][1], bf[nn][1], acc[mm][nn]);
                }
        }
    }

    // epilogue: C/D layout col = lane&15, row = (lane>>4)*4 + reg  [m89]
    int colb = n0 + wn * 64;
    int rowb = m0 + wm * 64;
    #pragma unroll
    for (int mm = 0; mm < 4; ++mm)
        #pragma unroll
        for (int nn = 0; nn < 4; ++nn) {
            f32x4 v = acc[mm][nn];
            int col = colb + nn * 16 + (lane & 15);
            #pragma unroll
            for (int j = 0; j < 4; ++j) {
                int row = rowb + mm * 16 + (lane >> 4) * 4 + j;
                if (MODE == 0) {
                    size_t oidx = (size_t)row * 512 + (col & 511);
                    if (col < 512) O0[oidx] = v[j];
                    else           O1[oidx] = v[j];
                } else {
                    size_t oidx = (size_t)row * 512 + col;
                    O0[oidx] = v[j] + Dvec[col] * uIn[oidx];
                }
            }
        }
}

// ---------------------------------------------------------------------------
// scan phase A: per-chunk state sum only (no per-step writes)
// ---------------------------------------------------------------------------
__global__ __launch_bounds__(P_DIM) void scan_sums(
    const float* __restrict__ bur, const float* __restrict__ bui,
    const float* __restrict__ lbr, const float* __restrict__ lbi,
    float* __restrict__ bcr, float* __restrict__ bci)
{
    int p = threadIdx.x;
    int c = blockIdx.x;
    float lr = lbr[p], li = lbi[p];
    float xr = 0.f, xi = 0.f;
    size_t base = (size_t)c * T_CH * P_DIM + p;
    #pragma unroll 4
    for (int k = 0; k < T_CH; ++k) {
        size_t idx = base + (size_t)k * P_DIM;
        float br = bur[idx], bi = bui[idx];
        float nr = fmaf(lr, xr, fmaf(-li, xi, br));
        float ni = fmaf(lr, xi, fmaf( li, xr, bi));
        xr = nr; xi = ni;
    }
    bcr[(size_t)c * P_DIM + p] = xr;
    bci[(size_t)c * P_DIM + p] = xi;
}

// ---------------------------------------------------------------------------
// scan phase B: exclusive scan across chunk aggregates with factor lambda^64
// ---------------------------------------------------------------------------
__global__ __launch_bounds__(P_DIM) void scan_chunks(
    const float* __restrict__ bcr, const float* __restrict__ bci,
    const float* __restrict__ l64r, const float* __restrict__ l64i,
    float* __restrict__ carr, float* __restrict__ cari)
{
    int p = threadIdx.x;
    float lr = l64r[p], li = l64i[p];
    float sr = 0.f, si = 0.f;
    #pragma unroll 4
    for (int c = 0; c < NC; ++c) {
        size_t idx = (size_t)c * P_DIM + p;
        carr[idx] = sr; cari[idx] = si;
        float br = bcr[idx], bi = bci[idx];
        float nr = fmaf(lr, sr, fmaf(-li, si, br));
        float ni = fmaf(lr, si, fmaf( li, sr, bi));
        sr = nr; si = ni;
    }
}

// ---------------------------------------------------------------------------
// scan phase C: redo local recurrence seeded with carry; emit x as bf16 hi/lo
// ---------------------------------------------------------------------------
__global__ __launch_bounds__(P_DIM) void scan_fix(
    const float* __restrict__ bur, const float* __restrict__ bui,
    const float* __restrict__ lbr, const float* __restrict__ lbi,
    const float* __restrict__ carr, const float* __restrict__ cari,
    u16* __restrict__ xrh, u16* __restrict__ xrl,
    u16* __restrict__ xih, u16* __restrict__ xil)
{
    int p = threadIdx.x;
    int c = blockIdx.x;
    float lr = lbr[p], li = lbi[p];
    float xr = carr[(size_t)c * P_DIM + p];
    float xi = cari[(size_t)c * P_DIM + p];
    size_t base = (size_t)c * T_CH * P_DIM + p;
    for (int k = 0; k < T_CH; ++k) {
        size_t idx = base + (size_t)k * P_DIM;
        float br = bur[idx], bi = bui[idx];
        float nr = fmaf(lr, xr, fmaf(-li, xi, br));
        float ni = fmaf(lr, xi, fmaf( li, xr, bi));
        xr = nr; xi = ni;
        u16 hr = f2bf(xr);
        xrh[idx] = hr; xrl[idx] = f2bf(xr - bf2f(hr));
        u16 hi2 = f2bf(xi);
        xih[idx] = hi2; xil[idx] = f2bf(xi - bf2f(hi2));
    }
}

// ---------------------------------------------------------------------------
extern "C" void kernel_launch(void* const* d_in, const int* in_sizes, int n_in,
                              void* d_out, int out_size, void* d_ws, size_t ws_size,
                              hipStream_t stream)
{
    const float* u        = (const float*)d_in[0];
    const float* Lre      = (const float*)d_in[1];
    const float* Lim      = (const float*)d_in[2];
    const float* Bre      = (const float*)d_in[3];
    const float* Bim      = (const float*)d_in[4];
    const float* Cre      = (const float*)d_in[5];
    const float* Cim      = (const float*)d_in[6];
    const float* D        = (const float*)d_in[7];
    const float* log_step = (const float*)d_in[8];
    float* out = (float*)d_out;

    // workspace layout (bytes); u_hi/u_lo alias xr_hi/xr_lo (disjoint lifetimes)
    char* w8 = (char*)d_ws;
    float* bur  = (float*)(w8);                              // 33,554,432
    float* bui  = (float*)(w8 + 33554432);                   // 33,554,432
    u16*   xih  = (u16*)(w8 + 67108864);                     // 16,777,216
    u16*   xil  = (u16*)(w8 + 83886080);                     // 16,777,216
    u16*   uh   = (u16*)(w8 + 100663296);                    // 16,777,216 (alias xrh)
    u16*   ul   = (u16*)(w8 + 117440512);                    // 16,777,216 (alias xrl)
    u16*   xrh  = uh;
    u16*   xrl  = ul;
    u16*   Bcat = (u16*)(w8 + 134217728);                    // 3,145,728
    u16*   Ccat = (u16*)(w8 + 137363456);                    // 3,145,728
    float* bcr  = (float*)(w8 + 140509184);                  // 4 x 524,288
    float* bci  = bcr + NCP;
    float* carr = bci + NCP;
    float* cari = carr + NCP;
    float* lbr  = cari + NCP;                                // 6 x 2,048
    float* lbi  = lbr + P_DIM;
    float* l64r = lbi + P_DIM;
    float* l64i = l64r + P_DIM;
    float* gre  = l64i + P_DIM;
    float* gim  = gre + P_DIM;

    prep_kernel<<<1, P_DIM, 0, stream>>>(Lre, Lim, log_step, lbr, lbi, l64r, l64i, gre, gim);
    convert_u<<<(int)(LH / 1024), 256, 0, stream>>>(u, uh, ul);
    build_bcat<<<(P_DIM * H_DIM) / 256, 256, 0, stream>>>(Bre, Bim, gre, gim, Bcat);
    build_ccat<<<(H_DIM * P_DIM) / 256, 256, 0, stream>>>(Cre, Cim, Ccat);

    // Bu GEMM: A segs [u_hi | u_lo | u_hi], B = Bcat (1024 x 1536) -> bur/bui
    gemm_mfma<1536, 8, 0><<<1024, 256, 0, stream>>>(
        uh, ul, uh, uh, uh, uh, Bcat, bur, bui, nullptr, nullptr);

    scan_sums<<<NC, P_DIM, 0, stream>>>(bur, bui, lbr, lbi, bcr, bci);
    scan_chunks<<<1, P_DIM, 0, stream>>>(bcr, bci, l64r, l64i, carr, cari);
    scan_fix<<<NC, P_DIM, 0, stream>>>(bur, bui, lbr, lbi, carr, cari, xrh, xrl, xih, xil);

    // y GEMM: A segs [xr_hi|xr_lo|xr_hi|xi_hi|xi_lo|xi_hi], B = Ccat (512 x 3072)
    gemm_mfma<3072, 4, 1><<<512, 256, 0, stream>>>(
        xrh, xrl, xrh, xih, xil, xih, Ccat, out, nullptr, D, u);
}